// Round 13
// baseline (1167.548 us; speedup 1.0000x reference)
//
#include <hip/hip_runtime.h>
#include <stdint.h>

typedef __attribute__((ext_vector_type(8))) _Float16 f16x8;
typedef __attribute__((ext_vector_type(4))) float f32x4;

namespace {
constexpr int NB = 32768;   // batch rows
constexpr int TD = 1024;    // token dim
constexpr int HD = 512;     // hidden dim
constexpr int KC = 8192;    // codebook size

// workspace layout (bytes)
constexpr size_t WS_H      = 0;                                   // [NB][512] fp32 h
constexpr size_t WS_CHF    = WS_H + (size_t)NB * HD * 4;          // [KC][512] f16 codebook
constexpr size_t WS_CSQ32  = WS_CHF + (size_t)KC * HD * 2;        // [KC] f32 ||c||^2
constexpr size_t WS_PART   = WS_CSQ32 + (size_t)KC * 4;           // [NB][16] u64 candidates
constexpr size_t WS_NEED   = WS_PART + (size_t)NB * 16 * 8;       // ~76.1 MB
constexpr size_t WS_H16    = WS_NEED;                             // [NB][512] f16 h (optional)
constexpr size_t WS_NEED2  = WS_H16 + (size_t)NB * HD * 2;        // ~108.1 MB
}

__device__ __forceinline__ void g2lds16(const void* g, void* l) {
    __builtin_amdgcn_global_load_lds(
        (const __attribute__((address_space(1))) void*)g,
        (__attribute__((address_space(3))) void*)l, 16, 0, 0);
}

// ================= K0a: codebook -> f16 copy (one wave per code row) =================
__global__ void k0_prep_cb(const float* __restrict__ cb, uint8_t* __restrict__ ws) {
    _Float16* chf = (_Float16*)(ws + WS_CHF);
    const int wv = threadIdx.x >> 6, lane = threadIdx.x & 63;
    const int row = blockIdx.x * 4 + wv;
    const size_t base = (size_t)row * HD + lane * 8;
    const float4 a = *(const float4*)&cb[base];
    const float4 b = *(const float4*)&cb[base + 4];
    const float cf[8] = {a.x, a.y, a.z, a.w, b.x, b.y, b.z, b.w};
    f16x8 hv;
    #pragma unroll
    for (int e = 0; e < 8; ++e) hv[e] = (_Float16)cf[e];
    *(f16x8*)&chf[base] = hv;
}

// ================= K0b: ||c||^2 — SEQUENTIAL fp32 fma chain (round-1-identical) =================
__global__ void k0_csq(const float* __restrict__ cb, uint8_t* __restrict__ ws) {
    float* csq32 = (float*)(ws + WS_CSQ32);
    const int code = blockIdx.x * 256 + threadIdx.x;
    const float* crow = &cb[(size_t)code * HD];
    float sq = 0.0f;
    #pragma unroll 4
    for (int kq = 0; kq < HD / 4; ++kq) {
        const float4 v = *(const float4*)&crow[kq * 4];
        sq = fmaf(v.x, v.x, sq);
        sq = fmaf(v.y, v.y, sq);
        sq = fmaf(v.z, v.z, sq);
        sq = fmaf(v.w, v.w, sq);
    }
    csq32[code] = sq;
}

// ================= K1: h = tokens @ W^T + b — 8x8 tile, SEQUENTIAL fp32 fma chain per output =================
// Thread covers rows {rx*4+i, 64+rx*4+i}: Tt reads at 16B lane-stride (2-way bank alias = free).
template<bool H16>
__launch_bounds__(256, 2)
__global__ void k1_hgemm(const float* __restrict__ tokens,
                         const float* __restrict__ W,
                         const float* __restrict__ bias,
                         uint8_t* __restrict__ ws) {
    __shared__ __align__(16) float Tt[32][132];   // tokens tile transposed [k][row], 128 rows
    __shared__ __align__(16) float Wt[32][132];   // W tile transposed      [k][hid], 128 hids
    float* h = (float*)(ws + WS_H);
    _Float16* h16 = (_Float16*)(ws + WS_H16);

    const int tid = threadIdx.x;
    const int rows0 = blockIdx.x * 128;
    const int hcol0 = blockIdx.y * 128;
    const int rx = tid & 15;    // rows rx*4..+3 and 64+rx*4..+3
    const int cx = tid >> 4;    // hids cx*8 .. +7
    const int srow = tid >> 1;  // staging row/hid 0..127
    const int shalf = tid & 1;  // staging k-half (16 floats each)

    float acc[8][8];
    #pragma unroll
    for (int i = 0; i < 8; ++i)
        #pragma unroll
        for (int j = 0; j < 8; ++j) acc[i][j] = 0.0f;

    // per-output single unbroken fp32 fma chain over k = 0..1023 ascending (round-1-identical)
    #pragma unroll 1
    for (int kt = 0; kt < TD; kt += 32) {
        __syncthreads();
        {
            const float* tsrc = &tokens[(size_t)(rows0 + srow) * TD + kt + shalf * 16];
            const float* wsrc = &W[(size_t)(hcol0 + srow) * TD + kt + shalf * 16];
            #pragma unroll
            for (int q = 0; q < 4; ++q) {
                const float4 tv = *(const float4*)&tsrc[q * 4];
                const float4 wv = *(const float4*)&wsrc[q * 4];
                const int k0 = shalf * 16 + q * 4;
                Tt[k0 + 0][srow] = tv.x; Tt[k0 + 1][srow] = tv.y;
                Tt[k0 + 2][srow] = tv.z; Tt[k0 + 3][srow] = tv.w;
                Wt[k0 + 0][srow] = wv.x; Wt[k0 + 1][srow] = wv.y;
                Wt[k0 + 2][srow] = wv.z; Wt[k0 + 3][srow] = wv.w;
            }
        }
        __syncthreads();
        #pragma unroll 2
        for (int kk = 0; kk < 32; ++kk) {
            const float4 a0 = *(const float4*)&Tt[kk][rx * 4];
            const float4 a1 = *(const float4*)&Tt[kk][64 + rx * 4];
            const float4 b0 = *(const float4*)&Wt[kk][cx * 8];
            const float4 b1 = *(const float4*)&Wt[kk][cx * 8 + 4];
            const float av[8] = {a0.x, a0.y, a0.z, a0.w, a1.x, a1.y, a1.z, a1.w};
            const float bv[8] = {b0.x, b0.y, b0.z, b0.w, b1.x, b1.y, b1.z, b1.w};
            #pragma unroll
            for (int i = 0; i < 8; ++i)
                #pragma unroll
                for (int j = 0; j < 8; ++j)
                    acc[i][j] = fmaf(av[i], bv[j], acc[i][j]);
        }
    }

    float bj[8];
    #pragma unroll
    for (int j = 0; j < 8; ++j) bj[j] = bias[hcol0 + cx * 8 + j];
    #pragma unroll
    for (int i = 0; i < 8; ++i) {
        const int row = rows0 + ((i < 4) ? (rx * 4 + i) : (64 + rx * 4 + (i - 4)));
        float o[8];
        #pragma unroll
        for (int j = 0; j < 8; ++j) o[j] = acc[i][j] + bj[j];
        float4 o0, o1;
        o0.x = o[0]; o0.y = o[1]; o0.z = o[2]; o0.w = o[3];
        o1.x = o[4]; o1.y = o[5]; o1.z = o[6]; o1.w = o[7];
        *(float4*)&h[(size_t)row * HD + hcol0 + cx * 8] = o0;
        *(float4*)&h[(size_t)row * HD + hcol0 + cx * 8 + 4] = o1;
        if constexpr (H16) {
            f16x8 hv;
            #pragma unroll
            for (int j = 0; j < 8; ++j) hv[j] = (_Float16)o[j];
            *(f16x8*)&h16[(size_t)row * HD + hcol0 + cx * 8] = hv;
        }
    }
}

// ================= K2: approx scores (f16 MFMA), K-step 128, BN=128, XOR-swizzled LDS =================
// R11 structure (two barriers per stage, acc[4][4], cand logic bit-identical to R7/9/11) with the
// K-step doubled 64->128: barriers per block halve, registers unchanged, LDS 32->64 KB.
// LDS layout: tile[row][chunk], chunk = 16B (8 f16), 16 chunks/row; stored swizzled:
// LDS[row][c] = orig[row][c ^ (row&7)]. g2lds16 dest linear; global source carries the inverse.
template<bool H16>
__launch_bounds__(256, 1)
__global__ void k2_score(uint8_t* __restrict__ ws) {
    __shared__ __align__(16) _Float16 At[128 * 128];   // 32 KB (aliased as dump after the loop)
    __shared__ __align__(16) _Float16 Bt[128 * 128];   // 32 KB
    const float* h = (const float*)(ws + WS_H);
    const _Float16* h16 = (const _Float16*)(ws + WS_H16);
    const _Float16* chf = (const _Float16*)(ws + WS_CHF);
    const float* csq32 = (const float*)(ws + WS_CSQ32);
    unsigned long long* part = (unsigned long long*)(ws + WS_PART);

    const int tid = threadIdx.x;
    const int l = tid & 63;
    const int w = tid >> 6;
    const int wr = w >> 1, wc = w & 1;
    const int rows0 = blockIdx.x * 128;
    const int codes0 = blockIdx.y * 2048;

    // staging geometry: each g2lds16 covers 4 rows x 16 chunks (1024 B).
    // lane l -> row (l>>4), dest chunk (l&15); source chunk inverse-swizzled by global row & 7.
    const int sr4 = l >> 4;                // row within 4-row group (0..3)

    unsigned long long cand0[16], cand1[16];
    #pragma unroll
    for (int s = 0; s < 16; ++s) { cand0[s] = ~0ull; cand1[s] = ~0ull; }

    #pragma unroll 1
    for (int cc = 0; cc < 16; ++cc) {
        const int codebase = codes0 + cc * 128;
        f32x4 acc[4][4];
        #pragma unroll
        for (int m = 0; m < 4; ++m)
            #pragma unroll
            for (int n = 0; n < 4; ++n) acc[m][n] = (f32x4)(0.0f);

        #pragma unroll 1
        for (int kt = 0; kt < HD; kt += 128) {
            __syncthreads();
            // B: 8 wave-loads of 4 code rows each (128 codes)
            #pragma unroll
            for (int i = 0; i < 8; ++i) {
                const int sub = w * 8 + i;
                const int row = sub * 4 + sr4;
                const int scnk = (l & 15) ^ (row & 7);
                g2lds16(chf + (size_t)(codebase + row) * HD + kt + scnk * 8,
                        Bt + sub * 512);
            }
            if constexpr (H16) {
                #pragma unroll
                for (int i = 0; i < 8; ++i) {
                    const int sub = w * 8 + i;
                    const int row = sub * 4 + sr4;
                    const int scnk = (l & 15) ^ (row & 7);
                    g2lds16(h16 + (size_t)(rows0 + row) * HD + kt + scnk * 8,
                            At + sub * 512);
                }
            } else {
                // reg-stage fp32 h, convert, swizzled ds_write: row arow, chunks ahalf*8+j
                const int arow = tid >> 1, ahalf = tid & 1;
                const float* hsrc = &h[(size_t)(rows0 + arow) * HD + kt + ahalf * 64];
                #pragma unroll
                for (int j = 0; j < 8; ++j) {
                    const float4 q0 = *(const float4*)&hsrc[j * 8];
                    const float4 q1 = *(const float4*)&hsrc[j * 8 + 4];
                    f16x8 v;
                    v[0] = (_Float16)q0.x; v[1] = (_Float16)q0.y;
                    v[2] = (_Float16)q0.z; v[3] = (_Float16)q0.w;
                    v[4] = (_Float16)q1.x; v[5] = (_Float16)q1.y;
                    v[6] = (_Float16)q1.z; v[7] = (_Float16)q1.w;
                    const int cs = (ahalf * 8 + j) ^ (arow & 7);
                    *(f16x8*)&At[arow * 128 + cs * 8] = v;
                }
            }
            __syncthreads();

            // fragments: row = (wr|wc)*64 + m*16 + (l&15); chunk = (s*4 + (l>>4)) ^ (l&7)
            // (row-term multiples of 8 vanish under &7, so the swizzle factor is l&7)
            #pragma unroll
            for (int s = 0; s < 4; ++s) {
                f16x8 af[4], bfr[4];
                #pragma unroll
                for (int m = 0; m < 4; ++m)
                    af[m] = *(const f16x8*)&At[(wr * 64 + m * 16 + (l & 15)) * 128 +
                                               (((s * 4 + (l >> 4)) ^ (l & 7)) * 8)];
                #pragma unroll
                for (int n = 0; n < 4; ++n)
                    bfr[n] = *(const f16x8*)&Bt[(wc * 64 + n * 16 + (l & 15)) * 128 +
                                                (((s * 4 + (l >> 4)) ^ (l & 7)) * 8)];
                #pragma unroll
                for (int m = 0; m < 4; ++m)
                    #pragma unroll
                    for (int n = 0; n < 4; ++n)
                        acc[m][n] = __builtin_amdgcn_mfma_f32_16x16x32_f16(af[m], bfr[n], acc[m][n], 0, 0, 0);
            }
        }

        // fold into per-lane top-2 (bit-identical to rounds 7/9/11)
        #pragma unroll
        for (int n = 0; n < 4; ++n) {
            const int code = codebase + wc * 64 + n * 16 + (l & 15);
            const float cs = csq32[code];
            #pragma unroll
            for (int m = 0; m < 4; ++m)
                #pragma unroll
                for (int reg = 0; reg < 4; ++reg) {
                    const float s = fmaf(-2.0f, acc[m][n][reg], cs);
                    const uint32_t b = __float_as_uint(s);
                    const uint32_t msk = (uint32_t)((int32_t)b >> 31);
                    const uint32_t key = b ^ (msk | 0x80000000u);
                    const unsigned long long k64 =
                        ((unsigned long long)key << 32) | (unsigned long long)(uint32_t)code;
                    const int slot = m * 4 + reg;
                    if (k64 < cand0[slot]) { cand1[slot] = cand0[slot]; cand0[slot] = k64; }
                    else if (k64 < cand1[slot]) { cand1[slot] = k64; }
                }
        }
    }

    // all LDS reads of At/Bt done; alias At's first 16 KB as the dump buffer
    __syncthreads();
    unsigned long long (*dump)[16] = (unsigned long long (*)[16])At;

    // pre-merge top-2 across 4-lane groups (masks 1,2), then dump (single writer per cell)
    #pragma unroll
    for (int m = 0; m < 4; ++m)
        #pragma unroll
        for (int reg = 0; reg < 4; ++reg) {
            const int slot = m * 4 + reg;
            unsigned long long c0 = cand0[slot], c1 = cand1[slot];
            #pragma unroll
            for (int mask = 1; mask < 4; mask <<= 1) {
                const unsigned long long o0 = __shfl_xor(c0, mask, 64);
                const unsigned long long o1 = __shfl_xor(c1, mask, 64);
                if (o0 < c0) { c1 = (c0 < o1) ? c0 : o1; c0 = o0; }
                else         { c1 = (c1 < o0) ? c1 : o0; }
            }
            if ((l & 3) == 0) {
                const int rloc = wr * 64 + m * 16 + (l >> 4) * 4 + reg;
                const int g = (l >> 2) & 3;
                dump[rloc][wc * 8 + g * 2 + 0] = c0;
                dump[rloc][wc * 8 + g * 2 + 1] = c1;
            }
        }
    __syncthreads();

    // one thread per row: serial top-4 of the 16 entries (order-independent, single writer)
    if (tid < 128) {
        unsigned long long t0 = ~0ull, t1 = ~0ull, t2 = ~0ull, t3 = ~0ull;
        #pragma unroll 1
        for (int e = 0; e < 16; ++e) {
            const unsigned long long v = dump[tid][e];
            if (v < t0)      { t3 = t2; t2 = t1; t1 = t0; t0 = v; }
            else if (v < t1) { t3 = t2; t2 = t1; t1 = v; }
            else if (v < t2) { t3 = t2; t2 = v; }
            else if (v < t3) { t3 = v; }
        }
        const size_t pbase = (size_t)(rows0 + tid) * 16 + blockIdx.y * 4;
        part[pbase + 0] = t0;
        part[pbase + 1] = t1;
        part[pbase + 2] = t2;
        part[pbase + 3] = t3;
    }
}

// ================= K3: rescore 16 candidates with round-1-identical fp32 arithmetic =================
__launch_bounds__(256, 4)
__global__ void k3_rescore(const float* __restrict__ codebook,
                           const uint8_t* __restrict__ ws,
                           int* __restrict__ out) {
    const float* h = (const float*)(ws + WS_H);
    const float* csq32 = (const float*)(ws + WS_CSQ32);
    const unsigned long long* part = (const unsigned long long*)(ws + WS_PART);
    __shared__ unsigned long long red[16][16];

    const int tid = threadIdx.x;
    const int rloc = tid >> 4;          // local row 0..15
    const int slot = tid & 15;          // candidate slot
    const int row = blockIdx.x * 16 + rloc;

    const int idx = (int)(uint32_t)(part[(size_t)row * 16 + slot] & 0xFFFFFFFFull);
    const float* hrow = &h[(size_t)row * HD];
    const float* crow = &codebook[(size_t)idx * HD];

    // hc: sequential fp32 fma chain over k = 0..511 (round-1-identical)
    float hc = 0.0f;
    #pragma unroll 4
    for (int kq = 0; kq < HD / 4; ++kq) {
        const float4 hv = *(const float4*)&hrow[kq * 4];
        const float4 cv = *(const float4*)&crow[kq * 4];
        hc = fmaf(hv.x, cv.x, hc);
        hc = fmaf(hv.y, cv.y, hc);
        hc = fmaf(hv.z, cv.z, hc);
        hc = fmaf(hv.w, cv.w, hc);
    }
    const float s = fmaf(-2.0f, hc, csq32[idx]);   // round-1-identical final op

    const uint32_t b = __float_as_uint(s);
    const uint32_t key = (b & 0x80000000u) ? ~b : (b | 0x80000000u);
    red[rloc][slot] = ((unsigned long long)key << 32) | (unsigned long long)(uint32_t)idx;
    __syncthreads();

    // one thread per row: min over 16 (tie -> lowest code index, via packed key)
    if (tid < 16) {
        unsigned long long m = red[tid][0];
        #pragma unroll
        for (int e = 1; e < 16; ++e) {
            const unsigned long long v = red[tid][e];
            if (v < m) m = v;
        }
        out[blockIdx.x * 16 + tid] = (int)(uint32_t)(m & 0xFFFFFFFFull);
    }
}

// ================= Fallback (round-1 fp32 kernel, proven) if ws too small =================
__launch_bounds__(256, 1)
__global__ void qenc_fallback(const float* __restrict__ tokens,
                              const float* __restrict__ W,
                              const float* __restrict__ bias,
                              const float* __restrict__ codebook,
                              int* __restrict__ out)
{
    __shared__ __align__(16) float h_t[HD][64];
    __shared__ __align__(16) float stage[32 * 256];
    const int tid = threadIdx.x;
    const int rowbase = blockIdx.x * 64;
    {
        const int tx = tid & 15, ty = tid >> 4, sr = tid >> 2, sq = tid & 3;
        float* Wt = stage;
        float* Tt = stage + 32 * 64;
        #pragma unroll 1
        for (int hb = 0; hb < HD; hb += 64) {
            float acc[4][4];
            #pragma unroll
            for (int i = 0; i < 4; ++i)
                #pragma unroll
                for (int j = 0; j < 4; ++j) acc[i][j] = 0.0f;
            #pragma unroll 1
            for (int kt = 0; kt < TD; kt += 32) {
                __syncthreads();
                const float4 w0 = *(const float4*)&W[(hb + sr) * TD + kt + sq * 8];
                const float4 w1 = *(const float4*)&W[(hb + sr) * TD + kt + sq * 8 + 4];
                const float4 t0 = *(const float4*)&tokens[(rowbase + sr) * TD + kt + sq * 8];
                const float4 t1 = *(const float4*)&tokens[(rowbase + sr) * TD + kt + sq * 8 + 4];
                Wt[(sq * 8 + 0) * 64 + sr] = w0.x; Wt[(sq * 8 + 1) * 64 + sr] = w0.y;
                Wt[(sq * 8 + 2) * 64 + sr] = w0.z; Wt[(sq * 8 + 3) * 64 + sr] = w0.w;
                Wt[(sq * 8 + 4) * 64 + sr] = w1.x; Wt[(sq * 8 + 5) * 64 + sr] = w1.y;
                Wt[(sq * 8 + 6) * 64 + sr] = w1.z; Wt[(sq * 8 + 7) * 64 + sr] = w1.w;
                Tt[(sq * 8 + 0) * 64 + sr] = t0.x; Tt[(sq * 8 + 1) * 64 + sr] = t0.y;
                Tt[(sq * 8 + 2) * 64 + sr] = t0.z; Tt[(sq * 8 + 3) * 64 + sr] = t0.w;
                Tt[(sq * 8 + 4) * 64 + sr] = t1.x; Tt[(sq * 8 + 5) * 64 + sr] = t1.y;
                Tt[(sq * 8 + 6) * 64 + sr] = t1.z; Tt[(sq * 8 + 7) * 64 + sr] = t1.w;
                __syncthreads();
                #pragma unroll 8
                for (int kk = 0; kk < 32; ++kk) {
                    const float4 wv = *(const float4*)&Wt[kk * 64 + ty * 4];
                    const float4 tv = *(const float4*)&Tt[kk * 64 + tx * 4];
                    const float wf[4] = {wv.x, wv.y, wv.z, wv.w};
                    const float tf[4] = {tv.x, tv.y, tv.z, tv.w};
                    #pragma unroll
                    for (int i = 0; i < 4; ++i)
                        #pragma unroll
                        for (int j = 0; j < 4; ++j)
                            acc[i][j] = fmaf(wf[i], tf[j], acc[i][j]);
                }
            }
            #pragma unroll
            for (int i = 0; i < 4; ++i) {
                const float bb = bias[hb + ty * 4 + i];
                float4 o; o.x = acc[i][0] + bb; o.y = acc[i][1] + bb;
                o.z = acc[i][2] + bb; o.w = acc[i][3] + bb;
                *(float4*)&h_t[hb + ty * 4 + i][tx * 4] = o;
            }
        }
    }
    __syncthreads();
    {
        const int tx = tid & 31, ty = tid >> 5, sc = tid >> 3, sf = tid & 7;
        float bv[2][4]; int bi[2][4];
        #pragma unroll
        for (int ii = 0; ii < 2; ++ii)
            #pragma unroll
            for (int i = 0; i < 4; ++i) { bv[ii][i] = 3.4e38f; bi[ii][i] = 0; }
        #pragma unroll 1
        for (int cbase = 0; cbase < KC; cbase += 256) {
            float acc[2][2][4][4];
            #pragma unroll
            for (int ii = 0; ii < 2; ++ii)
                #pragma unroll
                for (int jj = 0; jj < 2; ++jj)
                    #pragma unroll
                    for (int i = 0; i < 4; ++i)
                        #pragma unroll
                        for (int j = 0; j < 4; ++j) acc[ii][jj][i][j] = 0.0f;
            float csqv = 0.0f;
            #pragma unroll 1
            for (int kt = 0; kt < HD; kt += 32) {
                __syncthreads();
                #pragma unroll
                for (int cg = 0; cg < 8; ++cg) {
                    const int c = cg * 32 + sc;
                    const float4 v = *(const float4*)&codebook[(cbase + c) * HD + kt + sf * 4];
                    stage[(sf * 4 + 0) * 256 + c] = v.x;
                    stage[(sf * 4 + 1) * 256 + c] = v.y;
                    stage[(sf * 4 + 2) * 256 + c] = v.z;
                    stage[(sf * 4 + 3) * 256 + c] = v.w;
                }
                __syncthreads();
                #pragma unroll 8
                for (int kk = 0; kk < 32; ++kk) {
                    const float v = stage[kk * 256 + tid];
                    csqv = fmaf(v, v, csqv);
                }
                #pragma unroll 4
                for (int kk = 0; kk < 32; ++kk) {
                    const float4 h0 = *(const float4*)&h_t[kt + kk][ty * 4];
                    const float4 h1 = *(const float4*)&h_t[kt + kk][ty * 4 + 32];
                    const float4 c0 = *(const float4*)&stage[kk * 256 + tx * 4];
                    const float4 c1 = *(const float4*)&stage[kk * 256 + 128 + tx * 4];
                    const float ha[2][4] = {{h0.x, h0.y, h0.z, h0.w}, {h1.x, h1.y, h1.z, h1.w}};
                    const float cf2[2][4] = {{c0.x, c0.y, c0.z, c0.w}, {c1.x, c1.y, c1.z, c1.w}};
                    #pragma unroll
                    for (int ii = 0; ii < 2; ++ii)
                        #pragma unroll
                        for (int jj = 0; jj < 2; ++jj)
                            #pragma unroll
                            for (int i = 0; i < 4; ++i)
                                #pragma unroll
                                for (int j = 0; j < 4; ++j)
                                    acc[ii][jj][i][j] = fmaf(ha[ii][i], cf2[jj][j], acc[ii][jj][i][j]);
                }
            }
            __syncthreads();
            stage[tid] = csqv;
            __syncthreads();
            #pragma unroll
            for (int jj = 0; jj < 2; ++jj)
                #pragma unroll
                for (int j = 0; j < 4; ++j) {
                    const int cloc = jj * 128 + tx * 4 + j;
                    const float cs = stage[cloc];
                    const int code = cbase + cloc;
                    #pragma unroll
                    for (int ii = 0; ii < 2; ++ii)
                        #pragma unroll
                        for (int i = 0; i < 4; ++i) {
                            const float s = fmaf(-2.0f, acc[ii][jj][i][j], cs);
                            if (s < bv[ii][i] || (s == bv[ii][i] && code < bi[ii][i])) {
                                bv[ii][i] = s; bi[ii][i] = code;
                            }
                        }
                }
        }
        #pragma unroll
        for (int ii = 0; ii < 2; ++ii)
            #pragma unroll
            for (int i = 0; i < 4; ++i) {
                float v = bv[ii][i]; int idx = bi[ii][i];
                #pragma unroll
                for (int m = 1; m < 32; m <<= 1) {
                    const float ov = __shfl_xor(v, m, 64);
                    const int   oi = __shfl_xor(idx, m, 64);
                    if (ov < v || (ov == v && oi < idx)) { v = ov; idx = oi; }
                }
                if (tx == 0) out[rowbase + ii * 32 + ty * 4 + i] = idx;
            }
    }
}

extern "C" void kernel_launch(void* const* d_in, const int* in_sizes, int n_in,
                              void* d_out, int out_size, void* d_ws, size_t ws_size,
                              hipStream_t stream) {
    const float* tokens   = (const float*)d_in[0];
    const float* W        = (const float*)d_in[1];
    const float* bias     = (const float*)d_in[2];
    const float* codebook = (const float*)d_in[3];
    int* out = (int*)d_out;
    uint8_t* ws = (uint8_t*)d_ws;

    if (ws_size < WS_NEED) {
        qenc_fallback<<<NB / 64, 256, 0, stream>>>(tokens, W, bias, codebook, out);
        return;
    }
    k0_prep_cb<<<KC / 4, 256, 0, stream>>>(codebook, ws);
    k0_csq<<<KC / 256, 256, 0, stream>>>(codebook, ws);
    if (ws_size >= WS_NEED2) {
        k1_hgemm<true><<<dim3(NB / 128, HD / 128), 256, 0, stream>>>(tokens, W, bias, ws);
        k2_score<true><<<dim3(NB / 128, KC / 2048), 256, 0, stream>>>(ws);
    } else {
        k1_hgemm<false><<<dim3(NB / 128, HD / 128), 256, 0, stream>>>(tokens, W, bias, ws);
        k2_score<false><<<dim3(NB / 128, KC / 2048), 256, 0, stream>>>(ws);
    }
    k3_rescore<<<NB / 16, 256, 0, stream>>>(codebook, ws, out);
}

// Round 14
// 971.655 us; speedup vs baseline: 1.2016x; 1.2016x over previous
//
#include <hip/hip_runtime.h>
#include <stdint.h>

typedef __attribute__((ext_vector_type(8))) _Float16 f16x8;
typedef __attribute__((ext_vector_type(4))) float f32x4;

namespace {
constexpr int NB = 32768;   // batch rows
constexpr int TD = 1024;    // token dim
constexpr int HD = 512;     // hidden dim
constexpr int KC = 8192;    // codebook size

// workspace layout (bytes)
constexpr size_t WS_H      = 0;                                   // [NB][512] fp32 h
constexpr size_t WS_CHF    = WS_H + (size_t)NB * HD * 4;          // [KC][512] f16 codebook
constexpr size_t WS_CSQ32  = WS_CHF + (size_t)KC * HD * 2;        // [KC] f32 ||c||^2
constexpr size_t WS_PART   = WS_CSQ32 + (size_t)KC * 4;           // [NB][16] u64 candidates
constexpr size_t WS_NEED   = WS_PART + (size_t)NB * 16 * 8;       // ~76.1 MB
constexpr size_t WS_H16    = WS_NEED;                             // [NB][512] f16 h (optional)
constexpr size_t WS_NEED2  = WS_H16 + (size_t)NB * HD * 2;        // ~108.1 MB
}

__device__ __forceinline__ void g2lds16(const void* g, void* l) {
    __builtin_amdgcn_global_load_lds(
        (const __attribute__((address_space(1))) void*)g,
        (__attribute__((address_space(3))) void*)l, 16, 0, 0);
}

// ================= K0a: codebook -> f16 copy (one wave per code row) =================
__global__ void k0_prep_cb(const float* __restrict__ cb, uint8_t* __restrict__ ws) {
    _Float16* chf = (_Float16*)(ws + WS_CHF);
    const int wv = threadIdx.x >> 6, lane = threadIdx.x & 63;
    const int row = blockIdx.x * 4 + wv;
    const size_t base = (size_t)row * HD + lane * 8;
    const float4 a = *(const float4*)&cb[base];
    const float4 b = *(const float4*)&cb[base + 4];
    const float cf[8] = {a.x, a.y, a.z, a.w, b.x, b.y, b.z, b.w};
    f16x8 hv;
    #pragma unroll
    for (int e = 0; e < 8; ++e) hv[e] = (_Float16)cf[e];
    *(f16x8*)&chf[base] = hv;
}

// ================= K0b: ||c||^2 — SEQUENTIAL fp32 fma chain (round-1-identical) =================
__global__ void k0_csq(const float* __restrict__ cb, uint8_t* __restrict__ ws) {
    float* csq32 = (float*)(ws + WS_CSQ32);
    const int code = blockIdx.x * 256 + threadIdx.x;
    const float* crow = &cb[(size_t)code * HD];
    float sq = 0.0f;
    #pragma unroll 4
    for (int kq = 0; kq < HD / 4; ++kq) {
        const float4 v = *(const float4*)&crow[kq * 4];
        sq = fmaf(v.x, v.x, sq);
        sq = fmaf(v.y, v.y, sq);
        sq = fmaf(v.z, v.z, sq);
        sq = fmaf(v.w, v.w, sq);
    }
    csq32[code] = sq;
}

// ================= K1: h = tokens @ W^T + b — 8x8 tile, K-step 64, SEQUENTIAL fp32 fma chain =================
// Thread covers rows {rx*4+i, 64+rx*4+i}: Tt reads at 16B lane-stride (2-way bank alias = free).
// K-step 32->64 halves barrier count; per-output chain stays a single ascending k=0..1023 sequence.
template<bool H16>
__launch_bounds__(256, 2)
__global__ void k1_hgemm(const float* __restrict__ tokens,
                         const float* __restrict__ W,
                         const float* __restrict__ bias,
                         uint8_t* __restrict__ ws) {
    __shared__ __align__(16) float Tt[64][132];   // tokens tile transposed [k][row], 128 rows
    __shared__ __align__(16) float Wt[64][132];   // W tile transposed      [k][hid], 128 hids
    float* h = (float*)(ws + WS_H);
    _Float16* h16 = (_Float16*)(ws + WS_H16);

    const int tid = threadIdx.x;
    const int rows0 = blockIdx.x * 128;
    const int hcol0 = blockIdx.y * 128;
    const int rx = tid & 15;    // rows rx*4..+3 and 64+rx*4..+3
    const int cx = tid >> 4;    // hids cx*8 .. +7
    const int srow = tid >> 1;  // staging row/hid 0..127
    const int shalf = tid & 1;  // staging k-half (32 floats each)

    float acc[8][8];
    #pragma unroll
    for (int i = 0; i < 8; ++i)
        #pragma unroll
        for (int j = 0; j < 8; ++j) acc[i][j] = 0.0f;

    // per-output single unbroken fp32 fma chain over k = 0..1023 ascending (round-1-identical)
    #pragma unroll 1
    for (int kt = 0; kt < TD; kt += 64) {
        __syncthreads();
        {
            const float* tsrc = &tokens[(size_t)(rows0 + srow) * TD + kt + shalf * 32];
            const float* wsrc = &W[(size_t)(hcol0 + srow) * TD + kt + shalf * 32];
            #pragma unroll
            for (int q = 0; q < 8; ++q) {
                const float4 tv = *(const float4*)&tsrc[q * 4];
                const float4 wv = *(const float4*)&wsrc[q * 4];
                const int k0 = shalf * 32 + q * 4;
                Tt[k0 + 0][srow] = tv.x; Tt[k0 + 1][srow] = tv.y;
                Tt[k0 + 2][srow] = tv.z; Tt[k0 + 3][srow] = tv.w;
                Wt[k0 + 0][srow] = wv.x; Wt[k0 + 1][srow] = wv.y;
                Wt[k0 + 2][srow] = wv.z; Wt[k0 + 3][srow] = wv.w;
            }
        }
        __syncthreads();
        #pragma unroll 2
        for (int kk = 0; kk < 64; ++kk) {
            const float4 a0 = *(const float4*)&Tt[kk][rx * 4];
            const float4 a1 = *(const float4*)&Tt[kk][64 + rx * 4];
            const float4 b0 = *(const float4*)&Wt[kk][cx * 8];
            const float4 b1 = *(const float4*)&Wt[kk][cx * 8 + 4];
            const float av[8] = {a0.x, a0.y, a0.z, a0.w, a1.x, a1.y, a1.z, a1.w};
            const float bv[8] = {b0.x, b0.y, b0.z, b0.w, b1.x, b1.y, b1.z, b1.w};
            #pragma unroll
            for (int i = 0; i < 8; ++i)
                #pragma unroll
                for (int j = 0; j < 8; ++j)
                    acc[i][j] = fmaf(av[i], bv[j], acc[i][j]);
        }
    }

    float bj[8];
    #pragma unroll
    for (int j = 0; j < 8; ++j) bj[j] = bias[hcol0 + cx * 8 + j];
    #pragma unroll
    for (int i = 0; i < 8; ++i) {
        const int row = rows0 + ((i < 4) ? (rx * 4 + i) : (64 + rx * 4 + (i - 4)));
        float o[8];
        #pragma unroll
        for (int j = 0; j < 8; ++j) o[j] = acc[i][j] + bj[j];
        float4 o0, o1;
        o0.x = o[0]; o0.y = o[1]; o0.z = o[2]; o0.w = o[3];
        o1.x = o[4]; o1.y = o[5]; o1.z = o[6]; o1.w = o[7];
        *(float4*)&h[(size_t)row * HD + hcol0 + cx * 8] = o0;
        *(float4*)&h[(size_t)row * HD + hcol0 + cx * 8 + 4] = o1;
        if constexpr (H16) {
            f16x8 hv;
            #pragma unroll
            for (int j = 0; j < 8; ++j) hv[j] = (_Float16)o[j];
            *(f16x8*)&h16[(size_t)row * HD + hcol0 + cx * 8] = hv;
        }
    }
}

// ================= K2: approx scores (f16 MFMA), K-step 64, XOR-swizzled LDS =================
// BIT-EXACT restore of the 404-us configuration measured in round 11. Two barriers per stage,
// acc[4][4], VGPR ~104, LDS 32 KB -> 2 blocks/CU. Do not widen BN/BK (R12/R13: 1 block/CU = 640+).
template<bool H16>
__launch_bounds__(256, 2)
__global__ void k2_score(uint8_t* __restrict__ ws) {
    __shared__ __align__(16) _Float16 At[128 * 64];   // 16 KB (aliased as dump after the loop)
    __shared__ __align__(16) _Float16 Bt[128 * 64];   // 16 KB
    const float* h = (const float*)(ws + WS_H);
    const _Float16* h16 = (const _Float16*)(ws + WS_H16);
    const _Float16* chf = (const _Float16*)(ws + WS_CHF);
    const float* csq32 = (const float*)(ws + WS_CSQ32);
    unsigned long long* part = (unsigned long long*)(ws + WS_PART);

    const int tid = threadIdx.x;
    const int l = tid & 63;
    const int w = tid >> 6;
    const int wr = w >> 1, wc = w & 1;
    const int rows0 = blockIdx.x * 128;
    const int codes0 = blockIdx.y * 2048;

    // staging geometry: each g2lds16 covers 8 rows x 8 chunks (1024 B). lane l -> row l>>3, chunk l&7.
    const int sr = l >> 3;                 // row within 8-row group
    const int scnk = (l & 7) ^ sr;         // inverse-swizzled source chunk

    unsigned long long cand0[16], cand1[16];
    #pragma unroll
    for (int s = 0; s < 16; ++s) { cand0[s] = ~0ull; cand1[s] = ~0ull; }

    #pragma unroll 1
    for (int cc = 0; cc < 16; ++cc) {
        const int codebase = codes0 + cc * 128;
        f32x4 acc[4][4];
        #pragma unroll
        for (int m = 0; m < 4; ++m)
            #pragma unroll
            for (int n = 0; n < 4; ++n) acc[m][n] = (f32x4)(0.0f);

        #pragma unroll 1
        for (int kt = 0; kt < HD; kt += 64) {
            __syncthreads();
            // B: 4 sub-groups of 8 code rows per wave
            #pragma unroll
            for (int i = 0; i < 4; ++i) {
                const int sub = w * 4 + i;
                g2lds16(chf + (size_t)(codebase + sub * 8 + sr) * HD + kt + scnk * 8,
                        Bt + sub * 512);
            }
            if constexpr (H16) {
                #pragma unroll
                for (int i = 0; i < 4; ++i) {
                    const int sub = w * 4 + i;
                    g2lds16(h16 + (size_t)(rows0 + sub * 8 + sr) * HD + kt + scnk * 8,
                            At + sub * 512);
                }
            } else {
                // reg-stage fp32 h, convert, swizzled ds_write: row arow, chunks ahalf*4+j
                const int arow = tid >> 1, ahalf = tid & 1;
                const float* hsrc = &h[(size_t)(rows0 + arow) * HD + kt + ahalf * 32];
                #pragma unroll
                for (int j = 0; j < 4; ++j) {
                    const float4 q0 = *(const float4*)&hsrc[j * 8];
                    const float4 q1 = *(const float4*)&hsrc[j * 8 + 4];
                    f16x8 v;
                    v[0] = (_Float16)q0.x; v[1] = (_Float16)q0.y;
                    v[2] = (_Float16)q0.z; v[3] = (_Float16)q0.w;
                    v[4] = (_Float16)q1.x; v[5] = (_Float16)q1.y;
                    v[6] = (_Float16)q1.z; v[7] = (_Float16)q1.w;
                    const int cs = (ahalf * 4 + j) ^ (arow & 7);
                    *(f16x8*)&At[arow * 64 + cs * 8] = v;
                }
            }
            __syncthreads();

            // fragments: row = (wr|wc)*64 + m*16 + (l&15); chunk = (s*4 + (l>>4)) ^ (l&7)
            #pragma unroll
            for (int s = 0; s < 2; ++s) {
                f16x8 af[4], bfr[4];
                #pragma unroll
                for (int m = 0; m < 4; ++m)
                    af[m] = *(const f16x8*)&At[(wr * 64 + m * 16 + (l & 15)) * 64 +
                                               (((s * 4 + (l >> 4)) ^ (l & 7)) * 8)];
                #pragma unroll
                for (int n = 0; n < 4; ++n)
                    bfr[n] = *(const f16x8*)&Bt[(wc * 64 + n * 16 + (l & 15)) * 64 +
                                                (((s * 4 + (l >> 4)) ^ (l & 7)) * 8)];
                #pragma unroll
                for (int m = 0; m < 4; ++m)
                    #pragma unroll
                    for (int n = 0; n < 4; ++n)
                        acc[m][n] = __builtin_amdgcn_mfma_f32_16x16x32_f16(af[m], bfr[n], acc[m][n], 0, 0, 0);
            }
        }

        // fold into per-lane top-2 (bit-identical to rounds 7/9/11)
        #pragma unroll
        for (int n = 0; n < 4; ++n) {
            const int code = codebase + wc * 64 + n * 16 + (l & 15);
            const float cs = csq32[code];
            #pragma unroll
            for (int m = 0; m < 4; ++m)
                #pragma unroll
                for (int reg = 0; reg < 4; ++reg) {
                    const float s = fmaf(-2.0f, acc[m][n][reg], cs);
                    const uint32_t b = __float_as_uint(s);
                    const uint32_t msk = (uint32_t)((int32_t)b >> 31);
                    const uint32_t key = b ^ (msk | 0x80000000u);
                    const unsigned long long k64 =
                        ((unsigned long long)key << 32) | (unsigned long long)(uint32_t)code;
                    const int slot = m * 4 + reg;
                    if (k64 < cand0[slot]) { cand1[slot] = cand0[slot]; cand0[slot] = k64; }
                    else if (k64 < cand1[slot]) { cand1[slot] = k64; }
                }
        }
    }

    // all LDS reads of At/Bt done; alias At's 16 KB as the dump buffer
    __syncthreads();
    unsigned long long (*dump)[16] = (unsigned long long (*)[16])At;

    // pre-merge top-2 across 4-lane groups (masks 1,2), then dump (single writer per cell)
    #pragma unroll
    for (int m = 0; m < 4; ++m)
        #pragma unroll
        for (int reg = 0; reg < 4; ++reg) {
            const int slot = m * 4 + reg;
            unsigned long long c0 = cand0[slot], c1 = cand1[slot];
            #pragma unroll
            for (int mask = 1; mask < 4; mask <<= 1) {
                const unsigned long long o0 = __shfl_xor(c0, mask, 64);
                const unsigned long long o1 = __shfl_xor(c1, mask, 64);
                if (o0 < c0) { c1 = (c0 < o1) ? c0 : o1; c0 = o0; }
                else         { c1 = (c1 < o0) ? c1 : o0; }
            }
            if ((l & 3) == 0) {
                const int rloc = wr * 64 + m * 16 + (l >> 4) * 4 + reg;
                const int g = (l >> 2) & 3;
                dump[rloc][wc * 8 + g * 2 + 0] = c0;
                dump[rloc][wc * 8 + g * 2 + 1] = c1;
            }
        }
    __syncthreads();

    // one thread per row: serial top-4 of the 16 entries (order-independent, single writer)
    if (tid < 128) {
        unsigned long long t0 = ~0ull, t1 = ~0ull, t2 = ~0ull, t3 = ~0ull;
        #pragma unroll 1
        for (int e = 0; e < 16; ++e) {
            const unsigned long long v = dump[tid][e];
            if (v < t0)      { t3 = t2; t2 = t1; t1 = t0; t0 = v; }
            else if (v < t1) { t3 = t2; t2 = t1; t1 = v; }
            else if (v < t2) { t3 = t2; t2 = v; }
            else if (v < t3) { t3 = v; }
        }
        const size_t pbase = (size_t)(rows0 + tid) * 16 + blockIdx.y * 4;
        part[pbase + 0] = t0;
        part[pbase + 1] = t1;
        part[pbase + 2] = t2;
        part[pbase + 3] = t3;
    }
}

// ================= K3: rescore 16 candidates with round-1-identical fp32 arithmetic =================
__launch_bounds__(256, 4)
__global__ void k3_rescore(const float* __restrict__ codebook,
                           const uint8_t* __restrict__ ws,
                           int* __restrict__ out) {
    const float* h = (const float*)(ws + WS_H);
    const float* csq32 = (const float*)(ws + WS_CSQ32);
    const unsigned long long* part = (const unsigned long long*)(ws + WS_PART);
    __shared__ unsigned long long red[16][16];

    const int tid = threadIdx.x;
    const int rloc = tid >> 4;          // local row 0..15
    const int slot = tid & 15;          // candidate slot
    const int row = blockIdx.x * 16 + rloc;

    const int idx = (int)(uint32_t)(part[(size_t)row * 16 + slot] & 0xFFFFFFFFull);
    const float* hrow = &h[(size_t)row * HD];
    const float* crow = &codebook[(size_t)idx * HD];

    // hc: sequential fp32 fma chain over k = 0..511 (round-1-identical)
    float hc = 0.0f;
    #pragma unroll 4
    for (int kq = 0; kq < HD / 4; ++kq) {
        const float4 hv = *(const float4*)&hrow[kq * 4];
        const float4 cv = *(const float4*)&crow[kq * 4];
        hc = fmaf(hv.x, cv.x, hc);
        hc = fmaf(hv.y, cv.y, hc);
        hc = fmaf(hv.z, cv.z, hc);
        hc = fmaf(hv.w, cv.w, hc);
    }
    const float s = fmaf(-2.0f, hc, csq32[idx]);   // round-1-identical final op

    const uint32_t b = __float_as_uint(s);
    const uint32_t key = (b & 0x80000000u) ? ~b : (b | 0x80000000u);
    red[rloc][slot] = ((unsigned long long)key << 32) | (unsigned long long)(uint32_t)idx;
    __syncthreads();

    // one thread per row: min over 16 (tie -> lowest code index, via packed key)
    if (tid < 16) {
        unsigned long long m = red[tid][0];
        #pragma unroll
        for (int e = 1; e < 16; ++e) {
            const unsigned long long v = red[tid][e];
            if (v < m) m = v;
        }
        out[blockIdx.x * 16 + tid] = (int)(uint32_t)(m & 0xFFFFFFFFull);
    }
}

// ================= Fallback (round-1 fp32 kernel, proven) if ws too small =================
__launch_bounds__(256, 1)
__global__ void qenc_fallback(const float* __restrict__ tokens,
                              const float* __restrict__ W,
                              const float* __restrict__ bias,
                              const float* __restrict__ codebook,
                              int* __restrict__ out)
{
    __shared__ __align__(16) float h_t[HD][64];
    __shared__ __align__(16) float stage[32 * 256];
    const int tid = threadIdx.x;
    const int rowbase = blockIdx.x * 64;
    {
        const int tx = tid & 15, ty = tid >> 4, sr = tid >> 2, sq = tid & 3;
        float* Wt = stage;
        float* Tt = stage + 32 * 64;
        #pragma unroll 1
        for (int hb = 0; hb < HD; hb += 64) {
            float acc[4][4];
            #pragma unroll
            for (int i = 0; i < 4; ++i)
                #pragma unroll
                for (int j = 0; j < 4; ++j) acc[i][j] = 0.0f;
            #pragma unroll 1
            for (int kt = 0; kt < TD; kt += 32) {
                __syncthreads();
                const float4 w0 = *(const float4*)&W[(hb + sr) * TD + kt + sq * 8];
                const float4 w1 = *(const float4*)&W[(hb + sr) * TD + kt + sq * 8 + 4];
                const float4 t0 = *(const float4*)&tokens[(rowbase + sr) * TD + kt + sq * 8];
                const float4 t1 = *(const float4*)&tokens[(rowbase + sr) * TD + kt + sq * 8 + 4];
                Wt[(sq * 8 + 0) * 64 + sr] = w0.x; Wt[(sq * 8 + 1) * 64 + sr] = w0.y;
                Wt[(sq * 8 + 2) * 64 + sr] = w0.z; Wt[(sq * 8 + 3) * 64 + sr] = w0.w;
                Wt[(sq * 8 + 4) * 64 + sr] = w1.x; Wt[(sq * 8 + 5) * 64 + sr] = w1.y;
                Wt[(sq * 8 + 6) * 64 + sr] = w1.z; Wt[(sq * 8 + 7) * 64 + sr] = w1.w;
                Tt[(sq * 8 + 0) * 64 + sr] = t0.x; Tt[(sq * 8 + 1) * 64 + sr] = t0.y;
                Tt[(sq * 8 + 2) * 64 + sr] = t0.z; Tt[(sq * 8 + 3) * 64 + sr] = t0.w;
                Tt[(sq * 8 + 4) * 64 + sr] = t1.x; Tt[(sq * 8 + 5) * 64 + sr] = t1.y;
                Tt[(sq * 8 + 6) * 64 + sr] = t1.z; Tt[(sq * 8 + 7) * 64 + sr] = t1.w;
                __syncthreads();
                #pragma unroll 8
                for (int kk = 0; kk < 32; ++kk) {
                    const float4 wv = *(const float4*)&Wt[kk * 64 + ty * 4];
                    const float4 tv = *(const float4*)&Tt[kk * 64 + tx * 4];
                    const float wf[4] = {wv.x, wv.y, wv.z, wv.w};
                    const float tf[4] = {tv.x, tv.y, tv.z, tv.w};
                    #pragma unroll
                    for (int i = 0; i < 4; ++i)
                        #pragma unroll
                        for (int j = 0; j < 4; ++j)
                            acc[i][j] = fmaf(wf[i], tf[j], acc[i][j]);
                }
            }
            #pragma unroll
            for (int i = 0; i < 4; ++i) {
                const float bb = bias[hb + ty * 4 + i];
                float4 o; o.x = acc[i][0] + bb; o.y = acc[i][1] + bb;
                o.z = acc[i][2] + bb; o.w = acc[i][3] + bb;
                *(float4*)&h_t[hb + ty * 4 + i][tx * 4] = o;
            }
        }
    }
    __syncthreads();
    {
        const int tx = tid & 31, ty = tid >> 5, sc = tid >> 3, sf = tid & 7;
        float bv[2][4]; int bi[2][4];
        #pragma unroll
        for (int ii = 0; ii < 2; ++ii)
            #pragma unroll
            for (int i = 0; i < 4; ++i) { bv[ii][i] = 3.4e38f; bi[ii][i] = 0; }
        #pragma unroll 1
        for (int cbase = 0; cbase < KC; cbase += 256) {
            float acc[2][2][4][4];
            #pragma unroll
            for (int ii = 0; ii < 2; ++ii)
                #pragma unroll
                for (int jj = 0; jj < 2; ++jj)
                    #pragma unroll
                    for (int i = 0; i < 4; ++i)
                        #pragma unroll
                        for (int j = 0; j < 4; ++j) acc[ii][jj][i][j] = 0.0f;
            float csqv = 0.0f;
            #pragma unroll 1
            for (int kt = 0; kt < HD; kt += 32) {
                __syncthreads();
                #pragma unroll
                for (int cg = 0; cg < 8; ++cg) {
                    const int c = cg * 32 + sc;
                    const float4 v = *(const float4*)&codebook[(cbase + c) * HD + kt + sf * 4];
                    stage[(sf * 4 + 0) * 256 + c] = v.x;
                    stage[(sf * 4 + 1) * 256 + c] = v.y;
                    stage[(sf * 4 + 2) * 256 + c] = v.z;
                    stage[(sf * 4 + 3) * 256 + c] = v.w;
                }
                __syncthreads();
                #pragma unroll 8
                for (int kk = 0; kk < 32; ++kk) {
                    const float v = stage[kk * 256 + tid];
                    csqv = fmaf(v, v, csqv);
                }
                #pragma unroll 4
                for (int kk = 0; kk < 32; ++kk) {
                    const float4 h0 = *(const float4*)&h_t[kt + kk][ty * 4];
                    const float4 h1 = *(const float4*)&h_t[kt + kk][ty * 4 + 32];
                    const float4 c0 = *(const float4*)&stage[kk * 256 + tx * 4];
                    const float4 c1 = *(const float4*)&stage[kk * 256 + 128 + tx * 4];
                    const float ha[2][4] = {{h0.x, h0.y, h0.z, h0.w}, {h1.x, h1.y, h1.z, h1.w}};
                    const float cf2[2][4] = {{c0.x, c0.y, c0.z, c0.w}, {c1.x, c1.y, c1.z, c1.w}};
                    #pragma unroll
                    for (int ii = 0; ii < 2; ++ii)
                        #pragma unroll
                        for (int jj = 0; jj < 2; ++jj)
                            #pragma unroll
                            for (int i = 0; i < 4; ++i)
                                #pragma unroll
                                for (int j = 0; j < 4; ++j)
                                    acc[ii][jj][i][j] = fmaf(ha[ii][i], cf2[jj][j], acc[ii][jj][i][j]);
                }
            }
            __syncthreads();
            stage[tid] = csqv;
            __syncthreads();
            #pragma unroll
            for (int jj = 0; jj < 2; ++jj)
                #pragma unroll
                for (int j = 0; j < 4; ++j) {
                    const int cloc = jj * 128 + tx * 4 + j;
                    const float cs = stage[cloc];
                    const int code = cbase + cloc;
                    #pragma unroll
                    for (int ii = 0; ii < 2; ++ii)
                        #pragma unroll
                        for (int i = 0; i < 4; ++i) {
                            const float s = fmaf(-2.0f, acc[ii][jj][i][j], cs);
                            if (s < bv[ii][i] || (s == bv[ii][i] && code < bi[ii][i])) {
                                bv[ii][i] = s; bi[ii][i] = code;
                            }
                        }
                }
        }
        #pragma unroll
        for (int ii = 0; ii < 2; ++ii)
            #pragma unroll
            for (int i = 0; i < 4; ++i) {
                float v = bv[ii][i]; int idx = bi[ii][i];
                #pragma unroll
                for (int m = 1; m < 32; m <<= 1) {
                    const float ov = __shfl_xor(v, m, 64);
                    const int   oi = __shfl_xor(idx, m, 64);
                    if (ov < v || (ov == v && oi < idx)) { v = ov; idx = oi; }
                }
                if (tx == 0) out[rowbase + ii * 32 + ty * 4 + i] = idx;
            }
    }
}

extern "C" void kernel_launch(void* const* d_in, const int* in_sizes, int n_in,
                              void* d_out, int out_size, void* d_ws, size_t ws_size,
                              hipStream_t stream) {
    const float* tokens   = (const float*)d_in[0];
    const float* W        = (const float*)d_in[1];
    const float* bias     = (const float*)d_in[2];
    const float* codebook = (const float*)d_in[3];
    int* out = (int*)d_out;
    uint8_t* ws = (uint8_t*)d_ws;

    if (ws_size < WS_NEED) {
        qenc_fallback<<<NB / 64, 256, 0, stream>>>(tokens, W, bias, codebook, out);
        return;
    }
    k0_prep_cb<<<KC / 4, 256, 0, stream>>>(codebook, ws);
    k0_csq<<<KC / 256, 256, 0, stream>>>(codebook, ws);
    if (ws_size >= WS_NEED2) {
        k1_hgemm<true><<<dim3(NB / 128, HD / 128), 256, 0, stream>>>(tokens, W, bias, ws);
        k2_score<true><<<dim3(NB / 128, KC / 2048), 256, 0, stream>>>(ws);
    } else {
        k1_hgemm<false><<<dim3(NB / 128, HD / 128), 256, 0, stream>>>(tokens, W, bias, ws);
        k2_score<false><<<dim3(NB / 128, KC / 2048), 256, 0, stream>>>(ws);
    }
    k3_rescore<<<NB / 16, 256, 0, stream>>>(codebook, ws, out);
}

// Round 15
// 928.272 us; speedup vs baseline: 1.2578x; 1.0467x over previous
//
#include <hip/hip_runtime.h>
#include <stdint.h>

typedef __attribute__((ext_vector_type(8))) _Float16 f16x8;
typedef __attribute__((ext_vector_type(4))) float f32x4;

namespace {
constexpr int NB = 32768;   // batch rows
constexpr int TD = 1024;    // token dim
constexpr int HD = 512;     // hidden dim
constexpr int KC = 8192;    // codebook size

// workspace layout (bytes)
constexpr size_t WS_H      = 0;                                   // [NB][512] fp32 h
constexpr size_t WS_CHF    = WS_H + (size_t)NB * HD * 4;          // [KC][512] f16 codebook
constexpr size_t WS_CSQ32  = WS_CHF + (size_t)KC * HD * 2;        // [KC] f32 ||c||^2
constexpr size_t WS_PART   = WS_CSQ32 + (size_t)KC * 4;           // [NB][16] u64 candidates
constexpr size_t WS_NEED   = WS_PART + (size_t)NB * 16 * 8;       // ~76.1 MB
constexpr size_t WS_H16    = WS_NEED;                             // [NB][512] f16 h (optional)
constexpr size_t WS_NEED2  = WS_H16 + (size_t)NB * HD * 2;        // ~108.1 MB
}

__device__ __forceinline__ void g2lds16(const void* g, void* l) {
    __builtin_amdgcn_global_load_lds(
        (const __attribute__((address_space(1))) void*)g,
        (__attribute__((address_space(3))) void*)l, 16, 0, 0);
}

// ================= K0a: codebook -> f16 copy (one wave per code row) =================
__global__ void k0_prep_cb(const float* __restrict__ cb, uint8_t* __restrict__ ws) {
    _Float16* chf = (_Float16*)(ws + WS_CHF);
    const int wv = threadIdx.x >> 6, lane = threadIdx.x & 63;
    const int row = blockIdx.x * 4 + wv;
    const size_t base = (size_t)row * HD + lane * 8;
    const float4 a = *(const float4*)&cb[base];
    const float4 b = *(const float4*)&cb[base + 4];
    const float cf[8] = {a.x, a.y, a.z, a.w, b.x, b.y, b.z, b.w};
    f16x8 hv;
    #pragma unroll
    for (int e = 0; e < 8; ++e) hv[e] = (_Float16)cf[e];
    *(f16x8*)&chf[base] = hv;
}

// ================= K0b: ||c||^2 — SEQUENTIAL fp32 fma chain (round-1-identical) =================
__global__ void k0_csq(const float* __restrict__ cb, uint8_t* __restrict__ ws) {
    float* csq32 = (float*)(ws + WS_CSQ32);
    const int code = blockIdx.x * 256 + threadIdx.x;
    const float* crow = &cb[(size_t)code * HD];
    float sq = 0.0f;
    #pragma unroll 4
    for (int kq = 0; kq < HD / 4; ++kq) {
        const float4 v = *(const float4*)&crow[kq * 4];
        sq = fmaf(v.x, v.x, sq);
        sq = fmaf(v.y, v.y, sq);
        sq = fmaf(v.z, v.z, sq);
        sq = fmaf(v.w, v.w, sq);
    }
    csq32[code] = sq;
}

// ================= K1: h = tokens @ W^T + b — 8x8 tile, K-step 32, SEQUENTIAL fp32 fma chain =================
// Best measured config (R12): K-step 32 keeps LDS at 33792 B (4 blocks/CU); thread covers rows
// {rx*4+i, 64+rx*4+i} so Tt reads are 16B lane-stride (2-way bank alias = free). Per-output chain
// is a single ascending k=0..1023 fp32 fma sequence (round-1-identical). Do NOT raise K-step
// (R14: 64 KB LDS -> 2 blocks/CU -> VALUBusy 71->58%, dur 408->478).
template<bool H16>
__launch_bounds__(256, 2)
__global__ void k1_hgemm(const float* __restrict__ tokens,
                         const float* __restrict__ W,
                         const float* __restrict__ bias,
                         uint8_t* __restrict__ ws) {
    __shared__ __align__(16) float Tt[32][132];   // tokens tile transposed [k][row], 128 rows
    __shared__ __align__(16) float Wt[32][132];   // W tile transposed      [k][hid], 128 hids
    float* h = (float*)(ws + WS_H);
    _Float16* h16 = (_Float16*)(ws + WS_H16);

    const int tid = threadIdx.x;
    const int rows0 = blockIdx.x * 128;
    const int hcol0 = blockIdx.y * 128;
    const int rx = tid & 15;    // rows rx*4..+3 and 64+rx*4..+3
    const int cx = tid >> 4;    // hids cx*8 .. +7
    const int srow = tid >> 1;  // staging row/hid 0..127
    const int shalf = tid & 1;  // staging k-half (16 floats each)

    float acc[8][8];
    #pragma unroll
    for (int i = 0; i < 8; ++i)
        #pragma unroll
        for (int j = 0; j < 8; ++j) acc[i][j] = 0.0f;

    // per-output single unbroken fp32 fma chain over k = 0..1023 ascending (round-1-identical)
    #pragma unroll 1
    for (int kt = 0; kt < TD; kt += 32) {
        __syncthreads();
        {
            const float* tsrc = &tokens[(size_t)(rows0 + srow) * TD + kt + shalf * 16];
            const float* wsrc = &W[(size_t)(hcol0 + srow) * TD + kt + shalf * 16];
            #pragma unroll
            for (int q = 0; q < 4; ++q) {
                const float4 tv = *(const float4*)&tsrc[q * 4];
                const float4 wv = *(const float4*)&wsrc[q * 4];
                const int k0 = shalf * 16 + q * 4;
                Tt[k0 + 0][srow] = tv.x; Tt[k0 + 1][srow] = tv.y;
                Tt[k0 + 2][srow] = tv.z; Tt[k0 + 3][srow] = tv.w;
                Wt[k0 + 0][srow] = wv.x; Wt[k0 + 1][srow] = wv.y;
                Wt[k0 + 2][srow] = wv.z; Wt[k0 + 3][srow] = wv.w;
            }
        }
        __syncthreads();
        #pragma unroll 2
        for (int kk = 0; kk < 32; ++kk) {
            const float4 a0 = *(const float4*)&Tt[kk][rx * 4];
            const float4 a1 = *(const float4*)&Tt[kk][64 + rx * 4];
            const float4 b0 = *(const float4*)&Wt[kk][cx * 8];
            const float4 b1 = *(const float4*)&Wt[kk][cx * 8 + 4];
            const float av[8] = {a0.x, a0.y, a0.z, a0.w, a1.x, a1.y, a1.z, a1.w};
            const float bv[8] = {b0.x, b0.y, b0.z, b0.w, b1.x, b1.y, b1.z, b1.w};
            #pragma unroll
            for (int i = 0; i < 8; ++i)
                #pragma unroll
                for (int j = 0; j < 8; ++j)
                    acc[i][j] = fmaf(av[i], bv[j], acc[i][j]);
        }
    }

    float bj[8];
    #pragma unroll
    for (int j = 0; j < 8; ++j) bj[j] = bias[hcol0 + cx * 8 + j];
    #pragma unroll
    for (int i = 0; i < 8; ++i) {
        const int row = rows0 + ((i < 4) ? (rx * 4 + i) : (64 + rx * 4 + (i - 4)));
        float o[8];
        #pragma unroll
        for (int j = 0; j < 8; ++j) o[j] = acc[i][j] + bj[j];
        float4 o0, o1;
        o0.x = o[0]; o0.y = o[1]; o0.z = o[2]; o0.w = o[3];
        o1.x = o[4]; o1.y = o[5]; o1.z = o[6]; o1.w = o[7];
        *(float4*)&h[(size_t)row * HD + hcol0 + cx * 8] = o0;
        *(float4*)&h[(size_t)row * HD + hcol0 + cx * 8 + 4] = o1;
        if constexpr (H16) {
            f16x8 hv;
            #pragma unroll
            for (int j = 0; j < 8; ++j) hv[j] = (_Float16)o[j];
            *(f16x8*)&h16[(size_t)row * HD + hcol0 + cx * 8] = hv;
        }
    }
}

// ================= K2: approx scores (f16 MFMA), K-step 64, XOR-swizzled LDS =================
// Best measured config (404 us, round 11). Two barriers per stage, acc[4][4], VGPR ~104,
// LDS 32 KB -> 2 blocks/CU. Do not widen BN/BK (R12/R13: 1 block/CU = 640+ us).
template<bool H16>
__launch_bounds__(256, 2)
__global__ void k2_score(uint8_t* __restrict__ ws) {
    __shared__ __align__(16) _Float16 At[128 * 64];   // 16 KB (aliased as dump after the loop)
    __shared__ __align__(16) _Float16 Bt[128 * 64];   // 16 KB
    const float* h = (const float*)(ws + WS_H);
    const _Float16* h16 = (const _Float16*)(ws + WS_H16);
    const _Float16* chf = (const _Float16*)(ws + WS_CHF);
    const float* csq32 = (const float*)(ws + WS_CSQ32);
    unsigned long long* part = (unsigned long long*)(ws + WS_PART);

    const int tid = threadIdx.x;
    const int l = tid & 63;
    const int w = tid >> 6;
    const int wr = w >> 1, wc = w & 1;
    const int rows0 = blockIdx.x * 128;
    const int codes0 = blockIdx.y * 2048;

    // staging geometry: each g2lds16 covers 8 rows x 8 chunks (1024 B). lane l -> row l>>3, chunk l&7.
    const int sr = l >> 3;                 // row within 8-row group
    const int scnk = (l & 7) ^ sr;         // inverse-swizzled source chunk

    unsigned long long cand0[16], cand1[16];
    #pragma unroll
    for (int s = 0; s < 16; ++s) { cand0[s] = ~0ull; cand1[s] = ~0ull; }

    #pragma unroll 1
    for (int cc = 0; cc < 16; ++cc) {
        const int codebase = codes0 + cc * 128;
        f32x4 acc[4][4];
        #pragma unroll
        for (int m = 0; m < 4; ++m)
            #pragma unroll
            for (int n = 0; n < 4; ++n) acc[m][n] = (f32x4)(0.0f);

        #pragma unroll 1
        for (int kt = 0; kt < HD; kt += 64) {
            __syncthreads();
            // B: 4 sub-groups of 8 code rows per wave
            #pragma unroll
            for (int i = 0; i < 4; ++i) {
                const int sub = w * 4 + i;
                g2lds16(chf + (size_t)(codebase + sub * 8 + sr) * HD + kt + scnk * 8,
                        Bt + sub * 512);
            }
            if constexpr (H16) {
                #pragma unroll
                for (int i = 0; i < 4; ++i) {
                    const int sub = w * 4 + i;
                    g2lds16(h16 + (size_t)(rows0 + sub * 8 + sr) * HD + kt + scnk * 8,
                            At + sub * 512);
                }
            } else {
                // reg-stage fp32 h, convert, swizzled ds_write: row arow, chunks ahalf*4+j
                const int arow = tid >> 1, ahalf = tid & 1;
                const float* hsrc = &h[(size_t)(rows0 + arow) * HD + kt + ahalf * 32];
                #pragma unroll
                for (int j = 0; j < 4; ++j) {
                    const float4 q0 = *(const float4*)&hsrc[j * 8];
                    const float4 q1 = *(const float4*)&hsrc[j * 8 + 4];
                    f16x8 v;
                    v[0] = (_Float16)q0.x; v[1] = (_Float16)q0.y;
                    v[2] = (_Float16)q0.z; v[3] = (_Float16)q0.w;
                    v[4] = (_Float16)q1.x; v[5] = (_Float16)q1.y;
                    v[6] = (_Float16)q1.z; v[7] = (_Float16)q1.w;
                    const int cs = (ahalf * 4 + j) ^ (arow & 7);
                    *(f16x8*)&At[arow * 64 + cs * 8] = v;
                }
            }
            __syncthreads();

            // fragments: row = (wr|wc)*64 + m*16 + (l&15); chunk = (s*4 + (l>>4)) ^ (l&7)
            #pragma unroll
            for (int s = 0; s < 2; ++s) {
                f16x8 af[4], bfr[4];
                #pragma unroll
                for (int m = 0; m < 4; ++m)
                    af[m] = *(const f16x8*)&At[(wr * 64 + m * 16 + (l & 15)) * 64 +
                                               (((s * 4 + (l >> 4)) ^ (l & 7)) * 8)];
                #pragma unroll
                for (int n = 0; n < 4; ++n)
                    bfr[n] = *(const f16x8*)&Bt[(wc * 64 + n * 16 + (l & 15)) * 64 +
                                                (((s * 4 + (l >> 4)) ^ (l & 7)) * 8)];
                #pragma unroll
                for (int m = 0; m < 4; ++m)
                    #pragma unroll
                    for (int n = 0; n < 4; ++n)
                        acc[m][n] = __builtin_amdgcn_mfma_f32_16x16x32_f16(af[m], bfr[n], acc[m][n], 0, 0, 0);
            }
        }

        // fold into per-lane top-2 (bit-identical to rounds 7/9/11)
        #pragma unroll
        for (int n = 0; n < 4; ++n) {
            const int code = codebase + wc * 64 + n * 16 + (l & 15);
            const float cs = csq32[code];
            #pragma unroll
            for (int m = 0; m < 4; ++m)
                #pragma unroll
                for (int reg = 0; reg < 4; ++reg) {
                    const float s = fmaf(-2.0f, acc[m][n][reg], cs);
                    const uint32_t b = __float_as_uint(s);
                    const uint32_t msk = (uint32_t)((int32_t)b >> 31);
                    const uint32_t key = b ^ (msk | 0x80000000u);
                    const unsigned long long k64 =
                        ((unsigned long long)key << 32) | (unsigned long long)(uint32_t)code;
                    const int slot = m * 4 + reg;
                    if (k64 < cand0[slot]) { cand1[slot] = cand0[slot]; cand0[slot] = k64; }
                    else if (k64 < cand1[slot]) { cand1[slot] = k64; }
                }
        }
    }

    // all LDS reads of At/Bt done; alias At's 16 KB as the dump buffer
    __syncthreads();
    unsigned long long (*dump)[16] = (unsigned long long (*)[16])At;

    // pre-merge top-2 across 4-lane groups (masks 1,2), then dump (single writer per cell)
    #pragma unroll
    for (int m = 0; m < 4; ++m)
        #pragma unroll
        for (int reg = 0; reg < 4; ++reg) {
            const int slot = m * 4 + reg;
            unsigned long long c0 = cand0[slot], c1 = cand1[slot];
            #pragma unroll
            for (int mask = 1; mask < 4; mask <<= 1) {
                const unsigned long long o0 = __shfl_xor(c0, mask, 64);
                const unsigned long long o1 = __shfl_xor(c1, mask, 64);
                if (o0 < c0) { c1 = (c0 < o1) ? c0 : o1; c0 = o0; }
                else         { c1 = (c1 < o0) ? c1 : o0; }
            }
            if ((l & 3) == 0) {
                const int rloc = wr * 64 + m * 16 + (l >> 4) * 4 + reg;
                const int g = (l >> 2) & 3;
                dump[rloc][wc * 8 + g * 2 + 0] = c0;
                dump[rloc][wc * 8 + g * 2 + 1] = c1;
            }
        }
    __syncthreads();

    // one thread per row: serial top-4 of the 16 entries (order-independent, single writer)
    if (tid < 128) {
        unsigned long long t0 = ~0ull, t1 = ~0ull, t2 = ~0ull, t3 = ~0ull;
        #pragma unroll 1
        for (int e = 0; e < 16; ++e) {
            const unsigned long long v = dump[tid][e];
            if (v < t0)      { t3 = t2; t2 = t1; t1 = t0; t0 = v; }
            else if (v < t1) { t3 = t2; t2 = t1; t1 = v; }
            else if (v < t2) { t3 = t2; t2 = v; }
            else if (v < t3) { t3 = v; }
        }
        const size_t pbase = (size_t)(rows0 + tid) * 16 + blockIdx.y * 4;
        part[pbase + 0] = t0;
        part[pbase + 1] = t1;
        part[pbase + 2] = t2;
        part[pbase + 3] = t3;
    }
}

// ================= K3: rescore 16 candidates with round-1-identical fp32 arithmetic =================
__launch_bounds__(256, 4)
__global__ void k3_rescore(const float* __restrict__ codebook,
                           const uint8_t* __restrict__ ws,
                           int* __restrict__ out) {
    const float* h = (const float*)(ws + WS_H);
    const float* csq32 = (const float*)(ws + WS_CSQ32);
    const unsigned long long* part = (const unsigned long long*)(ws + WS_PART);
    __shared__ unsigned long long red[16][16];

    const int tid = threadIdx.x;
    const int rloc = tid >> 4;          // local row 0..15
    const int slot = tid & 15;          // candidate slot
    const int row = blockIdx.x * 16 + rloc;

    const int idx = (int)(uint32_t)(part[(size_t)row * 16 + slot] & 0xFFFFFFFFull);
    const float* hrow = &h[(size_t)row * HD];
    const float* crow = &codebook[(size_t)idx * HD];

    // hc: sequential fp32 fma chain over k = 0..511 (round-1-identical)
    float hc = 0.0f;
    #pragma unroll 4
    for (int kq = 0; kq < HD / 4; ++kq) {
        const float4 hv = *(const float4*)&hrow[kq * 4];
        const float4 cv = *(const float4*)&crow[kq * 4];
        hc = fmaf(hv.x, cv.x, hc);
        hc = fmaf(hv.y, cv.y, hc);
        hc = fmaf(hv.z, cv.z, hc);
        hc = fmaf(hv.w, cv.w, hc);
    }
    const float s = fmaf(-2.0f, hc, csq32[idx]);   // round-1-identical final op

    const uint32_t b = __float_as_uint(s);
    const uint32_t key = (b & 0x80000000u) ? ~b : (b | 0x80000000u);
    red[rloc][slot] = ((unsigned long long)key << 32) | (unsigned long long)(uint32_t)idx;
    __syncthreads();

    // one thread per row: min over 16 (tie -> lowest code index, via packed key)
    if (tid < 16) {
        unsigned long long m = red[tid][0];
        #pragma unroll
        for (int e = 1; e < 16; ++e) {
            const unsigned long long v = red[tid][e];
            if (v < m) m = v;
        }
        out[blockIdx.x * 16 + tid] = (int)(uint32_t)(m & 0xFFFFFFFFull);
    }
}

// ================= Fallback (round-1 fp32 kernel, proven) if ws too small =================
__launch_bounds__(256, 1)
__global__ void qenc_fallback(const float* __restrict__ tokens,
                              const float* __restrict__ W,
                              const float* __restrict__ bias,
                              const float* __restrict__ codebook,
                              int* __restrict__ out)
{
    __shared__ __align__(16) float h_t[HD][64];
    __shared__ __align__(16) float stage[32 * 256];
    const int tid = threadIdx.x;
    const int rowbase = blockIdx.x * 64;
    {
        const int tx = tid & 15, ty = tid >> 4, sr = tid >> 2, sq = tid & 3;
        float* Wt = stage;
        float* Tt = stage + 32 * 64;
        #pragma unroll 1
        for (int hb = 0; hb < HD; hb += 64) {
            float acc[4][4];
            #pragma unroll
            for (int i = 0; i < 4; ++i)
                #pragma unroll
                for (int j = 0; j < 4; ++j) acc[i][j] = 0.0f;
            #pragma unroll 1
            for (int kt = 0; kt < TD; kt += 32) {
                __syncthreads();
                const float4 w0 = *(const float4*)&W[(hb + sr) * TD + kt + sq * 8];
                const float4 w1 = *(const float4*)&W[(hb + sr) * TD + kt + sq * 8 + 4];
                const float4 t0 = *(const float4*)&tokens[(rowbase + sr) * TD + kt + sq * 8];
                const float4 t1 = *(const float4*)&tokens[(rowbase + sr) * TD + kt + sq * 8 + 4];
                Wt[(sq * 8 + 0) * 64 + sr] = w0.x; Wt[(sq * 8 + 1) * 64 + sr] = w0.y;
                Wt[(sq * 8 + 2) * 64 + sr] = w0.z; Wt[(sq * 8 + 3) * 64 + sr] = w0.w;
                Wt[(sq * 8 + 4) * 64 + sr] = w1.x; Wt[(sq * 8 + 5) * 64 + sr] = w1.y;
                Wt[(sq * 8 + 6) * 64 + sr] = w1.z; Wt[(sq * 8 + 7) * 64 + sr] = w1.w;
                Tt[(sq * 8 + 0) * 64 + sr] = t0.x; Tt[(sq * 8 + 1) * 64 + sr] = t0.y;
                Tt[(sq * 8 + 2) * 64 + sr] = t0.z; Tt[(sq * 8 + 3) * 64 + sr] = t0.w;
                Tt[(sq * 8 + 4) * 64 + sr] = t1.x; Tt[(sq * 8 + 5) * 64 + sr] = t1.y;
                Tt[(sq * 8 + 6) * 64 + sr] = t1.z; Tt[(sq * 8 + 7) * 64 + sr] = t1.w;
                __syncthreads();
                #pragma unroll 8
                for (int kk = 0; kk < 32; ++kk) {
                    const float4 wv = *(const float4*)&Wt[kk * 64 + ty * 4];
                    const float4 tv = *(const float4*)&Tt[kk * 64 + tx * 4];
                    const float wf[4] = {wv.x, wv.y, wv.z, wv.w};
                    const float tf[4] = {tv.x, tv.y, tv.z, tv.w};
                    #pragma unroll
                    for (int i = 0; i < 4; ++i)
                        #pragma unroll
                        for (int j = 0; j < 4; ++j)
                            acc[i][j] = fmaf(wf[i], tf[j], acc[i][j]);
                }
            }
            #pragma unroll
            for (int i = 0; i < 4; ++i) {
                const float bb = bias[hb + ty * 4 + i];
                float4 o; o.x = acc[i][0] + bb; o.y = acc[i][1] + bb;
                o.z = acc[i][2] + bb; o.w = acc[i][3] + bb;
                *(float4*)&h_t[hb + ty * 4 + i][tx * 4] = o;
            }
        }
    }
    __syncthreads();
    {
        const int tx = tid & 31, ty = tid >> 5, sc = tid >> 3, sf = tid & 7;
        float bv[2][4]; int bi[2][4];
        #pragma unroll
        for (int ii = 0; ii < 2; ++ii)
            #pragma unroll
            for (int i = 0; i < 4; ++i) { bv[ii][i] = 3.4e38f; bi[ii][i] = 0; }
        #pragma unroll 1
        for (int cbase = 0; cbase < KC; cbase += 256) {
            float acc[2][2][4][4];
            #pragma unroll
            for (int ii = 0; ii < 2; ++ii)
                #pragma unroll
                for (int jj = 0; jj < 2; ++jj)
                    #pragma unroll
                    for (int i = 0; i < 4; ++i)
                        #pragma unroll
                        for (int j = 0; j < 4; ++j) acc[ii][jj][i][j] = 0.0f;
            float csqv = 0.0f;
            #pragma unroll 1
            for (int kt = 0; kt < HD; kt += 32) {
                __syncthreads();
                #pragma unroll
                for (int cg = 0; cg < 8; ++cg) {
                    const int c = cg * 32 + sc;
                    const float4 v = *(const float4*)&codebook[(cbase + c) * HD + kt + sf * 4];
                    stage[(sf * 4 + 0) * 256 + c] = v.x;
                    stage[(sf * 4 + 1) * 256 + c] = v.y;
                    stage[(sf * 4 + 2) * 256 + c] = v.z;
                    stage[(sf * 4 + 3) * 256 + c] = v.w;
                }
                __syncthreads();
                #pragma unroll 8
                for (int kk = 0; kk < 32; ++kk) {
                    const float v = stage[kk * 256 + tid];
                    csqv = fmaf(v, v, csqv);
                }
                #pragma unroll 4
                for (int kk = 0; kk < 32; ++kk) {
                    const float4 h0 = *(const float4*)&h_t[kt + kk][ty * 4];
                    const float4 h1 = *(const float4*)&h_t[kt + kk][ty * 4 + 32];
                    const float4 c0 = *(const float4*)&stage[kk * 256 + tx * 4];
                    const float4 c1 = *(const float4*)&stage[kk * 256 + 128 + tx * 4];
                    const float ha[2][4] = {{h0.x, h0.y, h0.z, h0.w}, {h1.x, h1.y, h1.z, h1.w}};
                    const float cf2[2][4] = {{c0.x, c0.y, c0.z, c0.w}, {c1.x, c1.y, c1.z, c1.w}};
                    #pragma unroll
                    for (int ii = 0; ii < 2; ++ii)
                        #pragma unroll
                        for (int jj = 0; jj < 2; ++jj)
                            #pragma unroll
                            for (int i = 0; i < 4; ++i)
                                #pragma unroll
                                for (int j = 0; j < 4; ++j)
                                    acc[ii][jj][i][j] = fmaf(ha[ii][i], cf2[jj][j], acc[ii][jj][i][j]);
                }
            }
            __syncthreads();
            stage[tid] = csqv;
            __syncthreads();
            #pragma unroll
            for (int jj = 0; jj < 2; ++jj)
                #pragma unroll
                for (int j = 0; j < 4; ++j) {
                    const int cloc = jj * 128 + tx * 4 + j;
                    const float cs = stage[cloc];
                    const int code = cbase + cloc;
                    #pragma unroll
                    for (int ii = 0; ii < 2; ++ii)
                        #pragma unroll
                        for (int i = 0; i < 4; ++i) {
                            const float s = fmaf(-2.0f, acc[ii][jj][i][j], cs);
                            if (s < bv[ii][i] || (s == bv[ii][i] && code < bi[ii][i])) {
                                bv[ii][i] = s; bi[ii][i] = code;
                            }
                        }
                }
        }
        #pragma unroll
        for (int ii = 0; ii < 2; ++ii)
            #pragma unroll
            for (int i = 0; i < 4; ++i) {
                float v = bv[ii][i]; int idx = bi[ii][i];
                #pragma unroll
                for (int m = 1; m < 32; m <<= 1) {
                    const float ov = __shfl_xor(v, m, 64);
                    const int   oi = __shfl_xor(idx, m, 64);
                    if (ov < v || (ov == v && oi < idx)) { v = ov; idx = oi; }
                }
                if (tx == 0) out[rowbase + ii * 32 + ty * 4 + i] = idx;
            }
    }
}

extern "C" void kernel_launch(void* const* d_in, const int* in_sizes, int n_in,
                              void* d_out, int out_size, void* d_ws, size_t ws_size,
                              hipStream_t stream) {
    const float* tokens   = (const float*)d_in[0];
    const float* W        = (const float*)d_in[1];
    const float* bias     = (const float*)d_in[2];
    const float* codebook = (const float*)d_in[3];
    int* out = (int*)d_out;
    uint8_t* ws = (uint8_t*)d_ws;

    if (ws_size < WS_NEED) {
        qenc_fallback<<<NB / 64, 256, 0, stream>>>(tokens, W, bias, codebook, out);
        return;
    }
    k0_prep_cb<<<KC / 4, 256, 0, stream>>>(codebook, ws);
    k0_csq<<<KC / 256, 256, 0, stream>>>(codebook, ws);
    if (ws_size >= WS_NEED2) {
        k1_hgemm<true><<<dim3(NB / 128, HD / 128), 256, 0, stream>>>(tokens, W, bias, ws);
        k2_score<true><<<dim3(NB / 128, KC / 2048), 256, 0, stream>>>(ws);
    } else {
        k1_hgemm<false><<<dim3(NB / 128, HD / 128), 256, 0, stream>>>(tokens, W, bias, ws);
        k2_score<false><<<dim3(NB / 128, KC / 2048), 256, 0, stream>>>(ws);
    }
    k3_rescore<<<NB / 16, 256, 0, stream>>>(codebook, ws, out);
}